// Round 15
// baseline (703.035 us; speedup 1.0000x reference)
//
#include <hip/hip_runtime.h>
#include <hip/hip_bf16.h>
#include <cstddef>

#define NN 1024
#define BB 2
#define TT 12
#define ZS 352   // zT/zcT row stride: [h(0..63), x2(64), m(65), pad, 4 slots @68: [hdiff(0..63), x2d(64), md(65), pad]]

typedef __attribute__((ext_vector_type(8))) short short8;
typedef __attribute__((ext_vector_type(4))) short short4v;
typedef __attribute__((ext_vector_type(4))) float f32x4;
typedef __hip_bfloat16 bf16;

__device__ __forceinline__ float sigmoidf_(float v) { return 1.0f / (1.0f + expf(-v)); }
__device__ __forceinline__ short bf16s(float f) { bf16 h = __float2bfloat16(f); return *reinterpret_cast<short*>(&h); }

// ---------------- one-time weight prep ----------------
__device__ __forceinline__ float mapcol(const float* src, int c) {
    if (c < 64) return src[2 + c];
    if (c == 64) return src[0];
    if (c == 65) return src[1];
    if (c < 68 || c >= 340) return 0.f;
    const int d = c - 68, bk = d / 68, off = d % 68;
    if (off < 64) return src[66 + bk * 66 + 2 + off];
    if (off == 64) return src[66 + bk * 66];
    if (off == 65) return src[66 + bk * 66 + 1];
    return 0.f;
}
__device__ __forceinline__ float mapcolz(const float* src, int c) {
    // zeroes the x2d/md columns (handled via in-launch xd correction in k_gates)
    if (c < 64) return src[2 + c];
    if (c == 64) return src[0];
    if (c == 65) return src[1];
    if (c < 68 || c >= 340) return 0.f;
    const int d = c - 68, bk = d / 68, off = d % 68;
    if (off < 64) return src[66 + bk * 66 + 2 + off];
    return 0.f;
}

__global__ __launch_bounds__(256) void k_prep(
    const float* __restrict__ Wgc, const float* __restrict__ bgc,
    const float* __restrict__ Wdin, const float* __restrict__ bdin,
    const float* __restrict__ Wlout, const float* __restrict__ blout,
    const float* __restrict__ Wfs,
    const float* __restrict__ Wr, const float* __restrict__ Wu, const float* __restrict__ Wc,
    float* __restrict__ Wcomb, float* __restrict__ bcomb, float* __restrict__ blout2,
    bf16* __restrict__ Wpre, bf16* __restrict__ Wrub, bf16* __restrict__ Wcb,
    bf16* __restrict__ Wlb, float* __restrict__ Wrux)
{
    const int idx = blockIdx.x * 256 + threadIdx.x;
    if (idx < 8448) {
        const int o = idx / 66, k = idx % 66;
        const float* g = Wgc + (size_t)(o & 63) * 128 + (o >> 6) * 64;
        float a = 0.f;
#pragma unroll 8
        for (int c = 0; c < 64; ++c) a += g[c] * Wdin[c * 66 + k];
        Wcomb[idx] = a;
    } else if (idx < 8576) {
        const int o = idx - 8448;
        const float* g = Wgc + (size_t)(o & 63) * 128 + (o >> 6) * 64;
        float a = 0.f;
#pragma unroll 8
        for (int c = 0; c < 64; ++c) a += g[c] * bdin[c];
        bcomb[o] = a;
    } else if (idx < 8640) {
        const int oc = idx - 8576;
        float a = blout[oc];
#pragma unroll 8
        for (int j = 0; j < 64; ++j) a += Wlout[(size_t)oc * 128 + j] * bgc[j];
        blout2[oc] = a;
    } else if (idx < 17856) {
        const int j = idx - 8640, r = j >> 6, k = j & 63;
        float v = 0.f;
        if (r == 0) v = Wfs[k];
        else if (r <= 128) {
            const int o = r - 1;
            const float* g = Wgc + (size_t)(o & 63) * 128 + (o >> 6) * 64;
#pragma unroll 8
            for (int c = 0; c < 64; ++c) v += g[c] * Wdin[c * 66 + 2 + k];
        }
        Wpre[j] = __float2bfloat16(v);
    } else if (idx < 62912) {
        const int j = idx - 17856, r = j / 352, c = j % 352;
        const float* src = (r < 64) ? (Wr + (size_t)r * 330) : (Wu + (size_t)(r - 64) * 330);
        Wrub[j] = __float2bfloat16(mapcolz(src, c));
    } else if (idx < 85440) {
        const int j = idx - 62912, r = j / 352, c = j % 352;
        Wcb[j] = __float2bfloat16(mapcol(Wc + (size_t)r * 330, c));
    } else if (idx < 93632) {
        const int j = idx - 85440;
        Wlb[j] = __float2bfloat16(Wlout[j]);
    } else if (idx < 94656) {
        const int j2 = idx - 93632, r = j2 >> 3, j = j2 & 7;
        const float* src = (r < 64) ? (Wr + (size_t)r * 330) : (Wu + (size_t)(r - 64) * 330);
        Wrux[j2] = src[66 + (j >> 1) * 66 + (j & 1)];
    }
}

// ---------------- adj fp32 -> bf16 (adjb) + transposed (adjtb) ----------------
__global__ __launch_bounds__(256) void k_cvtT(const float* __restrict__ adj,
                                              bf16* __restrict__ adjb, bf16* __restrict__ adjtb)
{
    const int sb = blockIdx.z;
    const int r0 = blockIdx.y * 64, c0 = blockIdx.x * 64;
    const float* A = adj + ((size_t)sb << 20);
    __shared__ short tile[64][72];
    const int tr = threadIdx.x >> 4, tc = (threadIdx.x & 15) * 4;
#pragma unroll
    for (int i = 0; i < 4; ++i) {
        const int r = tr + i * 16;
        float4 v = *reinterpret_cast<const float4*>(&A[(size_t)(r0 + r) * NN + c0 + tc]);
        short4v o = { bf16s(v.x), bf16s(v.y), bf16s(v.z), bf16s(v.w) };
        *reinterpret_cast<short4v*>(&adjb[((size_t)sb << 20) + (size_t)(r0 + r) * NN + c0 + tc]) = o;
        tile[r][tc + 0] = o.x; tile[r][tc + 1] = o.y; tile[r][tc + 2] = o.z; tile[r][tc + 3] = o.w;
    }
    __syncthreads();
#pragma unroll
    for (int i = 0; i < 4; ++i) {
        const int v = tr + i * 16;
        short4v o = { tile[tc + 0][v], tile[tc + 1][v], tile[tc + 2][v], tile[tc + 3][v] };
        *reinterpret_cast<short4v*>(&adjtb[((size_t)sb << 20) + (size_t)(c0 + v) * NN + r0 + tc]) = o;
    }
}

// ---------------- A^2: high-occupancy. 2048 blocks x 4 waves; wave = 16w x 32v ----------------
__global__ __launch_bounds__(256) void k_a2(const bf16* __restrict__ adjb,
                                            const bf16* __restrict__ adjtb,
                                            bf16* __restrict__ adj2b)
{
    const int L = blockIdx.x;              // 0..2047
    const int sb = L >> 9;
    const int rem = L & 511;
    const int wt = rem >> 5;               // 0..15
    const int vt = rem & 31;               // 0..31
    const int wave = threadIdx.x >> 6, lane = threadIdx.x & 63;
    const int lr = lane & 15, lq = lane >> 4;
    const int w0 = wt * 64 + wave * 16;
    const int v0 = vt * 32;
    const bf16* Ar = adjb + ((size_t)sb << 20) + (size_t)(w0 + lr) * NN + lq * 8;
    const bf16* AT = adjtb + ((size_t)sb << 20) + (size_t)(v0 + lr) * NN + lq * 8;
    f32x4 acc[2];
    acc[0] = (f32x4){0.f, 0.f, 0.f, 0.f};
    acc[1] = (f32x4){0.f, 0.f, 0.f, 0.f};
#pragma unroll 4
    for (int k0 = 0; k0 < NN; k0 += 32) {
        short8 af = *reinterpret_cast<const short8*>(Ar + k0);
        short8 b0 = *reinterpret_cast<const short8*>(AT + k0);
        short8 b1 = *reinterpret_cast<const short8*>(AT + (size_t)16 * NN + k0);
        acc[0] = __builtin_amdgcn_mfma_f32_16x16x32_bf16(af, b0, acc[0], 0, 0, 0);
        acc[1] = __builtin_amdgcn_mfma_f32_16x16x32_bf16(af, b1, acc[1], 0, 0, 0);
    }
    bf16* D = adj2b + ((size_t)sb << 20);
#pragma unroll
    for (int nb = 0; nb < 2; ++nb)
#pragma unroll
        for (int q = 0; q < 4; ++q)
            D[(size_t)(w0 + lq * 4 + q) * NN + v0 + nb * 16 + lr] = __float2bfloat16(acc[nb][q]);
}

// ---------------- pre (standalone, t=0) ----------------
__global__ __launch_bounds__(64) void k_pre(
    const bf16* __restrict__ Wpre, const bf16* __restrict__ zT,
    const float* __restrict__ Wcomb, const float* __restrict__ bcomb,
    const float* __restrict__ bfsp,
    const float* __restrict__ x, const int* __restrict__ mask,
    bf16* __restrict__ yb, float* __restrict__ pred, int t)
{
    const int lane = threadIdx.x & 63, lr = lane & 15, lq = lane >> 4;
    const int p = blockIdx.x * 16 + lr;
    const bf16* B = zT + (size_t)p * ZS;
    f32x4 acc[9];
#pragma unroll
    for (int m = 0; m < 9; ++m) acc[m] = (f32x4){0.f, 0.f, 0.f, 0.f};
#pragma unroll
    for (int ks = 0; ks < 2; ++ks) {
        short8 bfr = *reinterpret_cast<const short8*>(B + ks * 32 + lq * 8);
#pragma unroll
        for (int m = 0; m < 9; ++m) {
            short8 af = *reinterpret_cast<const short8*>(Wpre + (size_t)(m * 16 + lr) * 64 + ks * 32 + lq * 8);
            acc[m] = __builtin_amdgcn_mfma_f32_16x16x32_bf16(af, bfr, acc[m], 0, 0, 0);
        }
    }
    const int b = p >> 10, n = p & (NN - 1);
    const size_t xi = (size_t)p * TT + t;
    const float xs1v = acc[0][0] + bfsp[0];
    const float xs1 = __shfl(xs1v, lr);
    const int mi = mask[xi];
    const float mf = (float)mi;
    const float x1 = mi ? x[xi] : xs1;
    if (lq == 0) pred[xi] = xs1;
#pragma unroll
    for (int m = 0; m < 9; ++m)
#pragma unroll
        for (int q = 0; q < 4; ++q) {
            const int o = m * 16 + lq * 4 + q - 1;
            if (o >= 0 && o < 128) {
                const float val = acc[m][q] + Wcomb[o * 66] * x1 + Wcomb[o * 66 + 1] * mf + bcomb[o];
                yb[(size_t)(b * 128 + o) * NN + n] = __float2bfloat16(val);
            }
        }
}

// ---------------- difA: fused y-diffusion(both s)+dec2+xs2 (x<32) | 16-node h-diffusion blocks ----------------
__global__ __launch_bounds__(256) void k_difA(
    const bf16* __restrict__ adjb, const bf16* __restrict__ adj2b,
    const bf16* __restrict__ yb, const bf16* __restrict__ zbi,
    const bf16* __restrict__ Wlb, const float* __restrict__ blout2,
    const float* __restrict__ prelu_a, const float* __restrict__ Wro,
    const float* __restrict__ bro, const float* __restrict__ x,
    const int* __restrict__ mask, const float* __restrict__ hTf,
    float* __restrict__ imp, float* __restrict__ repr,
    bf16* __restrict__ zb, bf16* __restrict__ zcb,
    bf16* __restrict__ zT, bf16* __restrict__ zcT, int t)
{
    const int wave = threadIdx.x >> 6, lane = threadIdx.x & 63;
    const int lr = lane & 15, lq = lane >> 4;

    __shared__ f32x4 red[3][2][2][4][64];   // 48 KB
    __shared__ short gh[32][136];
    __shared__ float hf[32][68];
    __shared__ float lo_sm[32][68];

    if (blockIdx.y >= 2) {
        // ---------- 16-node h-diffusion block (x 0..63) ----------
        const int n0h = blockIdx.x * 16;
        const int i = blockIdx.y - 2;
        const int b = i & 1, s = (i >> 1) & 1, ord = i >> 2;
        const int sb = s * 2 + b;
        const bf16* M = (ord ? adj2b : adjb) + ((size_t)sb << 20);
        const bf16* A = M + (size_t)(n0h + lr) * NN + lq * 8;
        const bf16* Xp = zbi + ((size_t)(b * 66 + lr)) * NN + lq * 8;
        f32x4 acc[4];
#pragma unroll
        for (int m = 0; m < 4; ++m) acc[m] = (f32x4){0.f, 0.f, 0.f, 0.f};
        const int vbeg = wave * 256;
#pragma unroll 2
        for (int it = 0; it < 8; ++it) {
            const int v0 = vbeg + it * 32;
            short8 bfr = *reinterpret_cast<const short8*>(A + v0);
            short8 af[4];
#pragma unroll
            for (int m = 0; m < 4; ++m)
                af[m] = *reinterpret_cast<const short8*>(Xp + (size_t)m * 16 * NN + v0);
#pragma unroll
            for (int m = 0; m < 4; ++m)
                acc[m] = __builtin_amdgcn_mfma_f32_16x16x32_bf16(af[m], bfr, acc[m], 0, 0, 0);
        }
        if (wave > 0) {
#pragma unroll
            for (int m = 0; m < 4; ++m) red[wave - 1][0][0][m][lane] = acc[m];
        }
        __syncthreads();
        if (wave == 0) {
            const int p = b * NN + n0h + lr;
            bf16* dst = zT + (size_t)p * ZS + 68 + (s * 2 + ord) * 68;
#pragma unroll
            for (int m = 0; m < 4; ++m) {
                acc[m] += red[0][0][0][m][lane] + red[1][0][0][m][lane] + red[2][0][0][m][lane];
                short4v o = { bf16s(acc[m][0]), bf16s(acc[m][1]),
                              bf16s(acc[m][2]), bf16s(acc[m][3]) };
                *reinterpret_cast<short4v*>(dst + m * 16 + lq * 4) = o;
            }
        }
        return;
    }

    if (blockIdx.x >= 32) return;
    const int n0 = blockIdx.x * 32;
    const int b = blockIdx.y;
    f32x4 acc[2][2][4];
#pragma unroll
    for (int s = 0; s < 2; ++s)
#pragma unroll
        for (int nt = 0; nt < 2; ++nt)
#pragma unroll
            for (int m = 0; m < 4; ++m) acc[s][nt][m] = (f32x4){0.f, 0.f, 0.f, 0.f};
    {
        const int vbeg = wave * 256;
#pragma unroll 2
        for (int it = 0; it < 8; ++it) {
            const int v0 = vbeg + it * 32;
            short8 bfr[2][2], af[2][4];
#pragma unroll
            for (int s = 0; s < 2; ++s) {
                const bf16* M = adjb + ((size_t)(s * 2 + b) << 20);
#pragma unroll
                for (int nt = 0; nt < 2; ++nt)
                    bfr[s][nt] = *reinterpret_cast<const short8*>(M + (size_t)(n0 + nt * 16 + lr) * NN + v0 + lq * 8);
#pragma unroll
                for (int m = 0; m < 4; ++m)
                    af[s][m] = *reinterpret_cast<const short8*>(yb + (size_t)(b * 128 + s * 64 + m * 16 + lr) * NN + v0 + lq * 8);
            }
#pragma unroll
            for (int s = 0; s < 2; ++s)
#pragma unroll
                for (int nt = 0; nt < 2; ++nt)
#pragma unroll
                    for (int m = 0; m < 4; ++m)
                        acc[s][nt][m] = __builtin_amdgcn_mfma_f32_16x16x32_bf16(af[s][m], bfr[s][nt], acc[s][nt][m], 0, 0, 0);
        }
    }
    if (wave > 0) {
#pragma unroll
        for (int s = 0; s < 2; ++s)
#pragma unroll
            for (int nt = 0; nt < 2; ++nt)
#pragma unroll
                for (int m = 0; m < 4; ++m) red[wave - 1][s][nt][m][lane] = acc[s][nt][m];
    }
    if (wave == 1 || wave == 2) {
        const int nb = (wave - 1) * 16;
        for (int i = lane; i < 1024; i += 64) {
            const int node = nb + (i >> 6), oc = i & 63;
            const float hv = hTf[(size_t)(b * NN + n0 + node) * 64 + oc];
            hf[node][oc] = hv;
            gh[node][64 + oc] = bf16s(hv);
            repr[(((size_t)b * 128 + 64 + oc) * NN + (n0 + node)) * TT + t] = hv;
        }
    }
    __syncthreads();
    if (wave == 0) {
#pragma unroll
        for (int nt = 0; nt < 2; ++nt) {
#pragma unroll
            for (int m = 0; m < 4; ++m) {
                f32x4 g = acc[0][nt][m] + acc[1][nt][m];
#pragma unroll
                for (int w = 0; w < 3; ++w) g += red[w][0][nt][m][lane] + red[w][1][nt][m][lane];
                const int node = nt * 16 + lr;
#pragma unroll
                for (int q = 0; q < 4; ++q) gh[node][m * 16 + lq * 4 + q] = bf16s(g[q]);
            }
        }
    }
    __syncthreads();
    {
        f32x4 dacc[2];
#pragma unroll
        for (int nt = 0; nt < 2; ++nt) dacc[nt] = (f32x4){0.f, 0.f, 0.f, 0.f};
#pragma unroll
        for (int ks = 0; ks < 4; ++ks) {
            short8 af = *reinterpret_cast<const short8*>(Wlb + (size_t)(wave * 16 + lr) * 128 + ks * 32 + lq * 8);
#pragma unroll
            for (int nt = 0; nt < 2; ++nt) {
                short8 bfr = *reinterpret_cast<const short8*>(&gh[nt * 16 + lr][ks * 32 + lq * 8]);
                dacc[nt] = __builtin_amdgcn_mfma_f32_16x16x32_bf16(af, bfr, dacc[nt], 0, 0, 0);
            }
        }
        const float pa = prelu_a[0];
#pragma unroll
        for (int nt = 0; nt < 2; ++nt) {
            const int node = nt * 16 + lr;
#pragma unroll
            for (int q = 0; q < 4; ++q) {
                const int oc = wave * 16 + lq * 4 + q;
                float v = dacc[nt][q] + blout2[oc];
                v = (v >= 0.f) ? v : pa * v;
                repr[(((size_t)b * 128 + oc) * NN + (n0 + node)) * TT + t] = v;
                lo_sm[node][oc] = v;
            }
        }
    }
    __syncthreads();
    {
        const int node = threadIdx.x >> 3, sub = threadIdx.x & 7;
        float s = 0.f;
#pragma unroll
        for (int j = sub * 8; j < sub * 8 + 8; ++j)
            s += Wro[j] * lo_sm[node][j] + Wro[64 + j] * hf[node][j];
        s += __shfl_xor(s, 1); s += __shfl_xor(s, 2); s += __shfl_xor(s, 4);
        if (sub == 0) {
            const float xs2 = s + bro[0];
            const int n = n0 + node;
            const int p = b * NN + n;
            const size_t xi = (size_t)p * TT + t;
            imp[xi] = xs2;
            const int mi = mask[xi];
            const float x2 = mi ? x[xi] : xs2;
            const bf16 x2b = __float2bfloat16(x2);
            const bf16 mb = __float2bfloat16((float)mi);
            zb[((size_t)b * 66 + 64) * NN + n] = x2b;
            zb[((size_t)b * 66 + 65) * NN + n] = mb;
            zT[(size_t)p * ZS + 64] = x2b; zT[(size_t)p * ZS + 65] = mb;
            zcT[(size_t)p * ZS + 64] = x2b; zcT[(size_t)p * ZS + 65] = mb;
        }
    }
}

// ---------------- difN1: rh diffusion, 16-node tiles (512 blocks) ----------------
__global__ __launch_bounds__(256) void k_difN(
    const bf16* __restrict__ adjb, const bf16* __restrict__ adj2b,
    const bf16* __restrict__ zcb, bf16* __restrict__ zcT)
{
    const int i = blockIdx.y;
    const int b = i & 1, s = (i >> 1) & 1, ord = i >> 2;
    const int wave = threadIdx.x >> 6, lane = threadIdx.x & 63;
    const int lr = lane & 15, lq = lane >> 4;
    const int n0 = blockIdx.x * 16;
    const int sb = s * 2 + b;
    const bf16* M = (ord ? adj2b : adjb) + ((size_t)sb << 20);
    const bf16* A = M + (size_t)(n0 + lr) * NN + lq * 8;
    const bf16* Xp = zcb + ((size_t)(b * 66 + lr)) * NN + lq * 8;

    f32x4 acc[4];
#pragma unroll
    for (int m = 0; m < 4; ++m) acc[m] = (f32x4){0.f, 0.f, 0.f, 0.f};
    const int vbeg = wave * 256;
#pragma unroll 2
    for (int it = 0; it < 8; ++it) {
        const int v0 = vbeg + it * 32;
        short8 bfr = *reinterpret_cast<const short8*>(A + v0);
        short8 af[4];
#pragma unroll
        for (int m = 0; m < 4; ++m)
            af[m] = *reinterpret_cast<const short8*>(Xp + (size_t)m * 16 * NN + v0);
#pragma unroll
        for (int m = 0; m < 4; ++m)
            acc[m] = __builtin_amdgcn_mfma_f32_16x16x32_bf16(af[m], bfr, acc[m], 0, 0, 0);
    }
    __shared__ f32x4 red[3][4][64];
    if (wave > 0) {
#pragma unroll
        for (int m = 0; m < 4; ++m) red[wave - 1][m][lane] = acc[m];
    }
    __syncthreads();
    if (wave == 0) {
        const int p = b * NN + n0 + lr;
        bf16* dst = zcT + (size_t)p * ZS + 68 + (s * 2 + ord) * 68;
#pragma unroll
        for (int m = 0; m < 4; ++m) {
            acc[m] += red[0][m][lane] + red[1][m][lane] + red[2][m][lane];
            short4v o = { bf16s(acc[m][0]), bf16s(acc[m][1]),
                          bf16s(acc[m][2]), bf16s(acc[m][3]) };
            *reinterpret_cast<short4v*>(dst + m * 16 + lq * 4) = o;
        }
    }
}

// ---------------- gates: 12 waves = 4 GEMM (r/u) + 8 xd-diffusion (split-K) ----------------
__global__ __launch_bounds__(768) void k_gates(
    const bf16* __restrict__ Wrub, const bf16* __restrict__ zT,
    const float* __restrict__ br, const float* __restrict__ bu,
    const float* __restrict__ hTf,
    const bf16* __restrict__ adjb, const bf16* __restrict__ adj2b,
    const bf16* __restrict__ zb, const float* __restrict__ Wrux,
    float* __restrict__ uT, bf16* __restrict__ zcb, bf16* __restrict__ zcT)
{
    const int wave = threadIdx.x >> 6, lane = threadIdx.x & 63;
    const int lr = lane & 15, lq = lane >> 4;
    const int p = blockIdx.x * 16 + lr;
    const int b = blockIdx.x >> 6;
    const int n0 = (blockIdx.x & 63) * 16;
    const int n = p & (NN - 1);
    __shared__ float pxd[4][2][2][16];   // [combo][half][chan][lr]
    __shared__ float wxs[128][8];

    f32x4 acc[2];
    acc[0] = (f32x4){0.f, 0.f, 0.f, 0.f};
    acc[1] = (f32x4){0.f, 0.f, 0.f, 0.f};

    if (wave < 4) {
        const int ti = wave * 64 + lane;   // 0..255
        reinterpret_cast<float4*>(&wxs[0][0])[ti] = reinterpret_cast<const float4*>(Wrux)[ti];
        const bf16* B = zT + (size_t)p * ZS;
#pragma unroll 2
        for (int ks = 0; ks < 11; ++ks) {
            short8 bfr = *reinterpret_cast<const short8*>(B + ks * 32 + lq * 8);
#pragma unroll
            for (int mm = 0; mm < 2; ++mm) {
                short8 af = *reinterpret_cast<const short8*>(
                    Wrub + (size_t)(wave * 32 + mm * 16 + lr) * ZS + ks * 32 + lq * 8);
                acc[mm] = __builtin_amdgcn_mfma_f32_16x16x32_bf16(af, bfr, acc[mm], 0, 0, 0);
            }
        }
    } else {
        // xd diffusion: wave 4+bk -> half 0 of combo bk; wave 8+bk -> half 1
        const int j = wave - 4;            // 0..7
        const int bk = j & 3, half = j >> 2;
        const int s = bk >> 1, ord = bk & 1;
        const bf16* Mp = (ord ? adj2b : adjb) + ((size_t)(s * 2 + b) << 20)
                         + (size_t)(n0 + lr) * NN + lq * 8 + half * 512;
        const bf16* Xp = zb + (size_t)(b * 66 + 64 + lr) * NN + lq * 8 + half * 512;
        const short8 zsh = {0, 0, 0, 0, 0, 0, 0, 0};
        f32x4 a = (f32x4){0.f, 0.f, 0.f, 0.f};
#pragma unroll 4
        for (int it = 0; it < 16; ++it) {
            short8 afv = (lr < 2) ? *reinterpret_cast<const short8*>(Xp + it * 32) : zsh;
            short8 mv = *reinterpret_cast<const short8*>(Mp + it * 32);
            a = __builtin_amdgcn_mfma_f32_16x16x32_bf16(afv, mv, a, 0, 0, 0);
        }
        if (lq == 0) { pxd[bk][half][0][lr] = a[0]; pxd[bk][half][1][lr] = a[1]; }
    }
    __syncthreads();

    if (wave < 4) {
        float xdsum[8];
#pragma unroll
        for (int j2 = 0; j2 < 8; ++j2)   // j2 = bk*2 + chan
            xdsum[j2] = pxd[j2 >> 1][0][j2 & 1][lr] + pxd[j2 >> 1][1][j2 & 1][lr];
        if (wave < 2) {
#pragma unroll
            for (int mm = 0; mm < 2; ++mm) {
                short4v rq;
#pragma unroll
                for (int q = 0; q < 4; ++q) {
                    const int oc = wave * 32 + mm * 16 + lq * 4 + q;   // 0..63 (r rows)
                    float corr = 0.f;
#pragma unroll
                    for (int j = 0; j < 8; ++j) corr += wxs[oc][j] * xdsum[j];
                    const float rv = sigmoidf_(acc[mm][q] + corr + br[oc]);
                    const float rh = rv * hTf[(size_t)p * 64 + oc];
                    rq[q] = bf16s(rh);
                    zcb[((size_t)b * 66 + oc) * NN + n] = __float2bfloat16(rh);
                }
                *reinterpret_cast<short4v*>(&zcT[(size_t)p * ZS + (wave * 32 + mm * 16) + lq * 4]) = rq;
            }
        } else {
#pragma unroll
            for (int mm = 0; mm < 2; ++mm) {
                f32x4 uq;
#pragma unroll
                for (int q = 0; q < 4; ++q) {
                    const int ocu = (wave - 2) * 32 + mm * 16 + lq * 4 + q;  // 0..63 (u rows)
                    float corr = 0.f;
#pragma unroll
                    for (int j = 0; j < 8; ++j) corr += wxs[64 + ocu][j] * xdsum[j];
                    uq[q] = sigmoidf_(acc[mm][q] + corr + bu[ocu]);
                }
                *reinterpret_cast<f32x4*>(&uT[(size_t)p * 64 + (wave - 2) * 32 + mm * 16 + lq * 4]) = uq;
            }
        }
    } else if (wave < 8 && lq == 0) {
        const int bk = wave - 4;
        const float v0 = pxd[bk][0][0][lr] + pxd[bk][1][0][lr];
        const float v1 = pxd[bk][0][1][lr] + pxd[bk][1][1][lr];
        bf16* dst = zcT + (size_t)p * ZS + 68 + bk * 68 + 64;
        dst[0] = __float2bfloat16(v0);
        dst[1] = __float2bfloat16(v1);
    }
}

// ---------------- cellpre: 4-wave m-split cell + pre(t+1) via LDS transpose ----------------
__global__ __launch_bounds__(256) void k_cellpre(
    const bf16* __restrict__ Wcb, const bf16* __restrict__ zcT,
    const float* __restrict__ bc, const float* __restrict__ uT,
    float* __restrict__ hTf, bf16* __restrict__ zT, bf16* __restrict__ zb,
    const bf16* __restrict__ Wpre, const float* __restrict__ Wcomb,
    const float* __restrict__ bcomb, const float* __restrict__ bfsp,
    const float* __restrict__ x, const int* __restrict__ mask,
    bf16* __restrict__ yb, float* __restrict__ pred, int tn)
{
    const int wave = threadIdx.x >> 6, lane = threadIdx.x & 63;
    const int lr = lane & 15, lq = lane >> 4;
    const int p = blockIdx.x * 16 + lr;
    const int b = p >> 10, n = p & (NN - 1);
    __shared__ short hsm[16][72];
    __shared__ float xs1s[16];

    // ---- cell: wave handles m-tile == wave ----
    {
        const bf16* B = zcT + (size_t)p * ZS;
        f32x4 acc = (f32x4){0.f, 0.f, 0.f, 0.f};
#pragma unroll 2
        for (int ks = 0; ks < 11; ++ks) {
            short8 bfr = *reinterpret_cast<const short8*>(B + ks * 32 + lq * 8);
            short8 af = *reinterpret_cast<const short8*>(Wcb + (size_t)(wave * 16 + lr) * ZS + ks * 32 + lq * 8);
            acc = __builtin_amdgcn_mfma_f32_16x16x32_bf16(af, bfr, acc, 0, 0, 0);
        }
        f32x4 hq;
        short4v hb;
#pragma unroll
        for (int q = 0; q < 4; ++q) {
            const int oc = wave * 16 + lq * 4 + q;
            const float cv = tanhf(acc[q] + bc[oc]);
            const float uv = uT[(size_t)p * 64 + oc];
            const float ho = hTf[(size_t)p * 64 + oc];
            const float hn = uv * ho + (1.f - uv) * cv;
            hq[q] = hn;
            hb[q] = bf16s(hn);
            zb[((size_t)b * 66 + oc) * NN + n] = __float2bfloat16(hn);
        }
        *reinterpret_cast<f32x4*>(&hTf[(size_t)p * 64 + wave * 16 + lq * 4]) = hq;
        *reinterpret_cast<short4v*>(&zT[(size_t)p * ZS + wave * 16 + lq * 4]) = hb;
        *reinterpret_cast<short4v*>(&hsm[lr][wave * 16 + lq * 4]) = hb;
    }
    __syncthreads();

    // ---- pre(tn): wave0 tiles {0,1,2}; wave1 {3,4}; wave2 {5,6}; wave3 {7,8} ----
    {
        const int tbase = (wave == 0) ? 0 : 1 + wave * 2;
        const int tcnt = (wave == 0) ? 3 : 2;
        f32x4 acc[3];
#pragma unroll
        for (int m = 0; m < 3; ++m) acc[m] = (f32x4){0.f, 0.f, 0.f, 0.f};
#pragma unroll
        for (int ks = 0; ks < 2; ++ks) {
            short8 bfr = *reinterpret_cast<const short8*>(&hsm[lr][ks * 32 + lq * 8]);
#pragma unroll
            for (int m = 0; m < 3; ++m) {
                if (m < tcnt) {
                    const int mm = tbase + m;
                    short8 af = *reinterpret_cast<const short8*>(Wpre + (size_t)(mm * 16 + lr) * 64 + ks * 32 + lq * 8);
                    acc[m] = __builtin_amdgcn_mfma_f32_16x16x32_bf16(af, bfr, acc[m], 0, 0, 0);
                }
            }
        }
        if (wave == 0 && lq == 0) xs1s[lr] = acc[0][0] + bfsp[0];
        __syncthreads();
        const float xs1 = xs1s[lr];
        const size_t xi = (size_t)p * TT + tn;
        const int mi = mask[xi];
        const float mf = (float)mi;
        const float x1 = mi ? x[xi] : xs1;
        if (wave == 0 && lq == 0) pred[xi] = xs1;
#pragma unroll
        for (int m = 0; m < 3; ++m) {
            if (m < tcnt) {
                const int mm = tbase + m;
#pragma unroll
                for (int q = 0; q < 4; ++q) {
                    const int o = mm * 16 + lq * 4 + q - 1;
                    if (o >= 0 && o < 128) {
                        const float val = acc[m][q] + Wcomb[o * 66] * x1 + Wcomb[o * 66 + 1] * mf + bcomb[o];
                        yb[(size_t)(b * 128 + o) * NN + n] = __float2bfloat16(val);
                    }
                }
            }
        }
    }
}

extern "C" void kernel_launch(void* const* d_in, const int* in_sizes, int n_in,
                              void* d_out, int out_size, void* d_ws, size_t ws_size,
                              hipStream_t stream)
{
    const float* x     = (const float*)d_in[0];
    const int*   mask  = (const int*)  d_in[1];
    const float* adj   = (const float*)d_in[2];
    const float* Wr    = (const float*)d_in[3];
    const float* br    = (const float*)d_in[4];
    const float* Wu    = (const float*)d_in[5];
    const float* bu    = (const float*)d_in[6];
    const float* Wc    = (const float*)d_in[7];
    const float* bc    = (const float*)d_in[8];
    const float* Wfs   = (const float*)d_in[9];
    const float* bfs   = (const float*)d_in[10];
    const float* Wdin  = (const float*)d_in[11];
    const float* bdin  = (const float*)d_in[12];
    const float* Wgc   = (const float*)d_in[13];
    const float* bgc   = (const float*)d_in[14];
    const float* Wlout = (const float*)d_in[15];
    const float* blout = (const float*)d_in[16];
    const float* Wro   = (const float*)d_in[17];
    const float* bro   = (const float*)d_in[18];
    const float* pa    = (const float*)d_in[19];

    float* ws = (float*)d_ws;
    float* Wcomb  = ws + 0;          // 8448
    float* bcomb  = ws + 8448;       // 128
    float* blout2 = ws + 8576;       // 64
    float* Wrux   = ws + 8640;       // 1024
    float* uT     = ws + 272832;     // 131072
    float* hTf    = ws + 403904;     // 131072   <- memset region start
    bf16* bfp   = (bf16*)(ws + 534976);
    bf16* zb    = bfp + 0;           // 135168
    bf16* zcb   = bfp + 135168;      // 135168
    bf16* zT    = bfp + 270336;      // 720896
    bf16* zcT   = bfp + 991232;      // 720896   <- memset region end (bfp+1712128)
    bf16* adjb  = bfp + 1712128;     // 4194304
    bf16* adjtb = bfp + 5906432;     // 4194304
    bf16* adj2b = bfp + 10100736;    // 4194304
    bf16* yb    = bfp + 14295040;    // 262144
    bf16* Wpre  = bfp + 14557184;    // 9216
    bf16* Wrub  = bfp + 14566400;    // 45056
    bf16* Wcb   = bfp + 14611456;    // 22528
    bf16* Wlb   = bfp + 14633984;    // 8192

    float* imp  = (float*)d_out;
    float* pred = imp + (size_t)BB * NN * TT;
    float* repr = imp + (size_t)2 * BB * NN * TT;

    hipMemsetAsync(hTf, 0, 131072 * 4 + (size_t)1712128 * 2, stream);
    hipLaunchKernelGGL(k_prep, dim3(370), dim3(256), 0, stream,
                       Wgc, bgc, Wdin, bdin, Wlout, blout, Wfs, Wr, Wu, Wc,
                       Wcomb, bcomb, blout2, Wpre, Wrub, Wcb, Wlb, Wrux);
    hipLaunchKernelGGL(k_cvtT, dim3(16, 16, 4), dim3(256), 0, stream, adj, adjb, adjtb);
    hipLaunchKernelGGL(k_a2, dim3(2048), dim3(256), 0, stream, adjb, adjtb, adj2b);

    hipLaunchKernelGGL(k_pre, dim3(128), dim3(64), 0, stream,
                       Wpre, zT, Wcomb, bcomb, bfs, x, mask, yb, pred, 0);

    for (int t = 0; t < TT; ++t) {
        // t==0: h == 0, so all h-diffusions are zero — memset already wrote them.
        const int ny = (t > 0 && t < TT - 1) ? 10 : 2;
        hipLaunchKernelGGL(k_difA, dim3(64, ny), dim3(256), 0, stream,
                           adjb, adj2b, yb, zb, Wlb, blout2, pa, Wro, bro, x, mask,
                           hTf, imp, repr, zb, zcb, zT, zcT, t);
        if (t < TT - 1) {
            hipLaunchKernelGGL(k_gates, dim3(128), dim3(768), 0, stream,
                               Wrub, zT, br, bu, hTf, adjb, adj2b, zb, Wrux,
                               uT, zcb, zcT);
            if (t > 0) {   // t==0: rh == 0, diffusion is zero — memset already wrote it
                hipLaunchKernelGGL(k_difN, dim3(64, 8), dim3(256), 0, stream,
                                   adjb, adj2b, zcb, zcT);
            }
            hipLaunchKernelGGL(k_cellpre, dim3(128), dim3(256), 0, stream,
                               Wcb, zcT, bc, uT, hTf, zT, zb,
                               Wpre, Wcomb, bcomb, bfs, x, mask, yb, pred, t + 1);
        }
    }
}

// Round 16
// 627.205 us; speedup vs baseline: 1.1209x; 1.1209x over previous
//
#include <hip/hip_runtime.h>
#include <hip/hip_bf16.h>
#include <cstddef>

#define NN 1024
#define BB 2
#define TT 12
#define ZS 352   // zT/zcT row stride: [h(0..63), x2(64), m(65), pad, 4 slots @68: [hdiff(0..63), x2d(64), md(65), pad]]

typedef __attribute__((ext_vector_type(8))) short short8;
typedef __attribute__((ext_vector_type(4))) short short4v;
typedef __attribute__((ext_vector_type(4))) float f32x4;
typedef __hip_bfloat16 bf16;

__device__ __forceinline__ float sigmoidf_(float v) { return 1.0f / (1.0f + expf(-v)); }
__device__ __forceinline__ short bf16s(float f) { bf16 h = __float2bfloat16(f); return *reinterpret_cast<short*>(&h); }

__device__ __forceinline__ float mapcol(const float* src, int c) {
    if (c < 64) return src[2 + c];
    if (c == 64) return src[0];
    if (c == 65) return src[1];
    if (c < 68 || c >= 340) return 0.f;
    const int d = c - 68, bk = d / 68, off = d % 68;
    if (off < 64) return src[66 + bk * 66 + 2 + off];
    if (off == 64) return src[66 + bk * 66];
    if (off == 65) return src[66 + bk * 66 + 1];
    return 0.f;
}
__device__ __forceinline__ float mapcolz(const float* src, int c) {
    if (c < 64) return src[2 + c];
    if (c == 64) return src[0];
    if (c == 65) return src[1];
    if (c < 68 || c >= 340) return 0.f;
    const int d = c - 68, bk = d / 68, off = d % 68;
    if (off < 64) return src[66 + bk * 66 + 2 + off];
    return 0.f;
}

// ---------------- k_init: weight prep (blocks 0..369) | adj cvt+T (370..1393) | zero 3.95MB (1394..1457) ----------------
__global__ __launch_bounds__(256) void k_init(
    const float* __restrict__ Wgc, const float* __restrict__ bgc,
    const float* __restrict__ Wdin, const float* __restrict__ bdin,
    const float* __restrict__ Wlout, const float* __restrict__ blout,
    const float* __restrict__ Wfs,
    const float* __restrict__ Wr, const float* __restrict__ Wu, const float* __restrict__ Wc,
    const float* __restrict__ adj,
    float* __restrict__ Wcomb, float* __restrict__ bcomb, float* __restrict__ blout2,
    bf16* __restrict__ Wpre, bf16* __restrict__ Wrub, bf16* __restrict__ Wcb,
    bf16* __restrict__ Wlb, float* __restrict__ Wrux,
    bf16* __restrict__ adjb, bf16* __restrict__ adjtb, float* __restrict__ zeroBase)
{
    __shared__ short tile[64][72];
    const int B = blockIdx.x;
    if (B < 370) {
        const int idx = B * 256 + threadIdx.x;
        if (idx < 8448) {
            const int o = idx / 66, k = idx % 66;
            const float* g = Wgc + (size_t)(o & 63) * 128 + (o >> 6) * 64;
            float a = 0.f;
#pragma unroll 8
            for (int c = 0; c < 64; ++c) a += g[c] * Wdin[c * 66 + k];
            Wcomb[idx] = a;
        } else if (idx < 8576) {
            const int o = idx - 8448;
            const float* g = Wgc + (size_t)(o & 63) * 128 + (o >> 6) * 64;
            float a = 0.f;
#pragma unroll 8
            for (int c = 0; c < 64; ++c) a += g[c] * bdin[c];
            bcomb[o] = a;
        } else if (idx < 8640) {
            const int oc = idx - 8576;
            float a = blout[oc];
#pragma unroll 8
            for (int j = 0; j < 64; ++j) a += Wlout[(size_t)oc * 128 + j] * bgc[j];
            blout2[oc] = a;
        } else if (idx < 17856) {
            const int j = idx - 8640, r = j >> 6, k = j & 63;
            float v = 0.f;
            if (r == 0) v = Wfs[k];
            else if (r <= 128) {
                const int o = r - 1;
                const float* g = Wgc + (size_t)(o & 63) * 128 + (o >> 6) * 64;
#pragma unroll 8
                for (int c = 0; c < 64; ++c) v += g[c] * Wdin[c * 66 + 2 + k];
            }
            Wpre[j] = __float2bfloat16(v);
        } else if (idx < 62912) {
            const int j = idx - 17856, r = j / 352, c = j % 352;
            const float* src = (r < 64) ? (Wr + (size_t)r * 330) : (Wu + (size_t)(r - 64) * 330);
            Wrub[j] = __float2bfloat16(mapcolz(src, c));
        } else if (idx < 85440) {
            const int j = idx - 62912, r = j / 352, c = j % 352;
            Wcb[j] = __float2bfloat16(mapcol(Wc + (size_t)r * 330, c));
        } else if (idx < 93632) {
            const int j = idx - 85440;
            Wlb[j] = __float2bfloat16(Wlout[j]);
        } else if (idx < 94656) {
            const int j2 = idx - 93632, r = j2 >> 3, j = j2 & 7;
            const float* src = (r < 64) ? (Wr + (size_t)r * 330) : (Wu + (size_t)(r - 64) * 330);
            Wrux[j2] = src[66 + (j >> 1) * 66 + (j & 1)];
        }
    } else if (B < 1394) {
        const int L2 = B - 370;
        const int sb = L2 >> 8;
        const int rem = L2 & 255;
        const int r0 = (rem >> 4) * 64, c0 = (rem & 15) * 64;
        const float* A = adj + ((size_t)sb << 20);
        const int tr = threadIdx.x >> 4, tc = (threadIdx.x & 15) * 4;
#pragma unroll
        for (int i = 0; i < 4; ++i) {
            const int r = tr + i * 16;
            float4 v = *reinterpret_cast<const float4*>(&A[(size_t)(r0 + r) * NN + c0 + tc]);
            short4v o = { bf16s(v.x), bf16s(v.y), bf16s(v.z), bf16s(v.w) };
            *reinterpret_cast<short4v*>(&adjb[((size_t)sb << 20) + (size_t)(r0 + r) * NN + c0 + tc]) = o;
            tile[r][tc + 0] = o.x; tile[r][tc + 1] = o.y; tile[r][tc + 2] = o.z; tile[r][tc + 3] = o.w;
        }
        __syncthreads();
#pragma unroll
        for (int i = 0; i < 4; ++i) {
            const int v = tr + i * 16;
            short4v o = { tile[tc + 0][v], tile[tc + 1][v], tile[tc + 2][v], tile[tc + 3][v] };
            *reinterpret_cast<short4v*>(&adjtb[((size_t)sb << 20) + (size_t)(c0 + v) * NN + r0 + tc]) = o;
        }
    } else {
        float4* z4 = reinterpret_cast<float4*>(zeroBase);
        const float4 z = {0.f, 0.f, 0.f, 0.f};
        for (int i = (B - 1394) * 256 + threadIdx.x; i < 246784; i += 64 * 256) z4[i] = z;
    }
}

// ---------------- k_a2pre: A^2 (blocks 0..511, R8 config) | pre t=0 (512..639) ----------------
__global__ __launch_bounds__(256) void k_a2pre(
    const bf16* __restrict__ adjb, const bf16* __restrict__ adjtb, bf16* __restrict__ adj2b,
    const bf16* __restrict__ Wpre, const bf16* __restrict__ zT,
    const float* __restrict__ Wcomb, const float* __restrict__ bcomb,
    const float* __restrict__ bfsp,
    const float* __restrict__ x, const int* __restrict__ mask,
    bf16* __restrict__ yb, float* __restrict__ pred)
{
    const int wave = threadIdx.x >> 6, lane = threadIdx.x & 63;
    const int lr = lane & 15, lq = lane >> 4;
    if (blockIdx.x < 512) {
        const int L = blockIdx.x;
        const int xv = L >> 6;
        const int yz = L & 63;
        const int w0 = (yz & 15) * 64;
        const int sb = yz >> 4;
        const int v0 = xv * 128 + wave * 32;
        const bf16* AT = adjtb + ((size_t)sb << 20) + (size_t)(v0 + lr) * NN + lq * 8;
        const bf16* Ar = adjb + ((size_t)sb << 20) + (size_t)(w0 + lr) * NN + lq * 8;
        f32x4 acc[4][2];
#pragma unroll
        for (int m = 0; m < 4; ++m)
#pragma unroll
            for (int nb = 0; nb < 2; ++nb) acc[m][nb] = (f32x4){0.f, 0.f, 0.f, 0.f};
#pragma unroll 4
        for (int k0 = 0; k0 < NN; k0 += 32) {
            short8 bfr[2], af[4];
#pragma unroll
            for (int nb = 0; nb < 2; ++nb)
                bfr[nb] = *reinterpret_cast<const short8*>(AT + (size_t)nb * 16 * NN + k0);
#pragma unroll
            for (int m = 0; m < 4; ++m)
                af[m] = *reinterpret_cast<const short8*>(Ar + (size_t)m * 16 * NN + k0);
#pragma unroll
            for (int m = 0; m < 4; ++m)
#pragma unroll
                for (int nb = 0; nb < 2; ++nb)
                    acc[m][nb] = __builtin_amdgcn_mfma_f32_16x16x32_bf16(af[m], bfr[nb], acc[m][nb], 0, 0, 0);
        }
        bf16* D = adj2b + ((size_t)sb << 20);
#pragma unroll
        for (int m = 0; m < 4; ++m)
#pragma unroll
            for (int nb = 0; nb < 2; ++nb)
#pragma unroll
                for (int q = 0; q < 4; ++q)
                    D[(size_t)(w0 + m * 16 + lq * 4 + q) * NN + v0 + nb * 16 + lr] = __float2bfloat16(acc[m][nb][q]);
        return;
    }
    // ---- pre(t=0), wave 0 only ----
    if (wave != 0) return;
    const int p = (blockIdx.x - 512) * 16 + lr;
    const bf16* Bz = zT + (size_t)p * ZS;
    f32x4 acc[9];
#pragma unroll
    for (int m = 0; m < 9; ++m) acc[m] = (f32x4){0.f, 0.f, 0.f, 0.f};
#pragma unroll
    for (int ks = 0; ks < 2; ++ks) {
        short8 bfr = *reinterpret_cast<const short8*>(Bz + ks * 32 + lq * 8);
#pragma unroll
        for (int m = 0; m < 9; ++m) {
            short8 af = *reinterpret_cast<const short8*>(Wpre + (size_t)(m * 16 + lr) * 64 + ks * 32 + lq * 8);
            acc[m] = __builtin_amdgcn_mfma_f32_16x16x32_bf16(af, bfr, acc[m], 0, 0, 0);
        }
    }
    const int b = p >> 10, n = p & (NN - 1);
    const size_t xi = (size_t)p * TT;
    const float xs1v = acc[0][0] + bfsp[0];
    const float xs1 = __shfl(xs1v, lr);
    const int mi = mask[xi];
    const float mf = (float)mi;
    const float x1 = mi ? x[xi] : xs1;
    if (lq == 0) pred[xi] = xs1;
#pragma unroll
    for (int m = 0; m < 9; ++m)
#pragma unroll
        for (int q = 0; q < 4; ++q) {
            const int o = m * 16 + lq * 4 + q - 1;
            if (o >= 0 && o < 128) {
                const float val = acc[m][q] + Wcomb[o * 66] * x1 + Wcomb[o * 66 + 1] * mf + bcomb[o];
                yb[(size_t)(b * 128 + o) * NN + n] = __float2bfloat16(val);
            }
        }
}

// ---------------- difA: fused y-diffusion(both s)+dec2+xs2 | h-diffusion blocks (R14) ----------------
__global__ __launch_bounds__(256) void k_difA(
    const bf16* __restrict__ adjb, const bf16* __restrict__ adj2b,
    const bf16* __restrict__ yb, const bf16* __restrict__ zbi,
    const bf16* __restrict__ Wlb, const float* __restrict__ blout2,
    const float* __restrict__ prelu_a, const float* __restrict__ Wro,
    const float* __restrict__ bro, const float* __restrict__ x,
    const int* __restrict__ mask, const float* __restrict__ hTf,
    float* __restrict__ imp, float* __restrict__ repr,
    bf16* __restrict__ zb, bf16* __restrict__ zcb,
    bf16* __restrict__ zT, bf16* __restrict__ zcT, int t)
{
    const int wave = threadIdx.x >> 6, lane = threadIdx.x & 63;
    const int lr = lane & 15, lq = lane >> 4;
    const int n0 = blockIdx.x * 32;

    __shared__ f32x4 red[3][2][2][4][64];   // 48 KB
    __shared__ short gh[32][136];
    __shared__ float hf[32][68];
    __shared__ float lo_sm[32][68];

    if (blockIdx.y >= 2) {
        const int i = blockIdx.y - 2;
        const int b = i & 1, s = (i >> 1) & 1, ord = i >> 2;
        const int sb = s * 2 + b;
        const bf16* M = (ord ? adj2b : adjb) + ((size_t)sb << 20);
        const bf16* A = M + (size_t)(n0 + lr) * NN + lq * 8;
        const bf16* Xp = zbi + ((size_t)(b * 66 + lr)) * NN + lq * 8;
        f32x4 acc[2][4];
#pragma unroll
        for (int nt = 0; nt < 2; ++nt)
#pragma unroll
            for (int m = 0; m < 4; ++m) acc[nt][m] = (f32x4){0.f, 0.f, 0.f, 0.f};
        const int vbeg = wave * 256;
#pragma unroll 2
        for (int it = 0; it < 8; ++it) {
            const int v0 = vbeg + it * 32;
            short8 bfr[2], af[4];
#pragma unroll
            for (int nt = 0; nt < 2; ++nt)
                bfr[nt] = *reinterpret_cast<const short8*>(A + (size_t)nt * 16 * NN + v0);
#pragma unroll
            for (int m = 0; m < 4; ++m)
                af[m] = *reinterpret_cast<const short8*>(Xp + (size_t)m * 16 * NN + v0);
#pragma unroll
            for (int nt = 0; nt < 2; ++nt)
#pragma unroll
                for (int m = 0; m < 4; ++m)
                    acc[nt][m] = __builtin_amdgcn_mfma_f32_16x16x32_bf16(af[m], bfr[nt], acc[nt][m], 0, 0, 0);
        }
        if (wave > 0) {
#pragma unroll
            for (int nt = 0; nt < 2; ++nt)
#pragma unroll
                for (int m = 0; m < 4; ++m) red[wave - 1][0][nt][m][lane] = acc[nt][m];
        }
        __syncthreads();
        if (wave == 0) {
#pragma unroll
            for (int nt = 0; nt < 2; ++nt) {
#pragma unroll
                for (int m = 0; m < 4; ++m)
                    acc[nt][m] += red[0][0][nt][m][lane] + red[1][0][nt][m][lane] + red[2][0][nt][m][lane];
                const int p = b * NN + n0 + nt * 16 + lr;
                bf16* dst = zT + (size_t)p * ZS + 68 + (s * 2 + ord) * 68;
#pragma unroll
                for (int m = 0; m < 4; ++m) {
                    short4v o = { bf16s(acc[nt][m][0]), bf16s(acc[nt][m][1]),
                                  bf16s(acc[nt][m][2]), bf16s(acc[nt][m][3]) };
                    *reinterpret_cast<short4v*>(dst + m * 16 + lq * 4) = o;
                }
            }
        }
        return;
    }

    const int b = blockIdx.y;
    f32x4 acc[2][2][4];
#pragma unroll
    for (int s = 0; s < 2; ++s)
#pragma unroll
        for (int nt = 0; nt < 2; ++nt)
#pragma unroll
            for (int m = 0; m < 4; ++m) acc[s][nt][m] = (f32x4){0.f, 0.f, 0.f, 0.f};
    {
        const int vbeg = wave * 256;
#pragma unroll 2
        for (int it = 0; it < 8; ++it) {
            const int v0 = vbeg + it * 32;
            short8 bfr[2][2], af[2][4];
#pragma unroll
            for (int s = 0; s < 2; ++s) {
                const bf16* M = adjb + ((size_t)(s * 2 + b) << 20);
#pragma unroll
                for (int nt = 0; nt < 2; ++nt)
                    bfr[s][nt] = *reinterpret_cast<const short8*>(M + (size_t)(n0 + nt * 16 + lr) * NN + v0 + lq * 8);
#pragma unroll
                for (int m = 0; m < 4; ++m)
                    af[s][m] = *reinterpret_cast<const short8*>(yb + (size_t)(b * 128 + s * 64 + m * 16 + lr) * NN + v0 + lq * 8);
            }
#pragma unroll
            for (int s = 0; s < 2; ++s)
#pragma unroll
                for (int nt = 0; nt < 2; ++nt)
#pragma unroll
                    for (int m = 0; m < 4; ++m)
                        acc[s][nt][m] = __builtin_amdgcn_mfma_f32_16x16x32_bf16(af[s][m], bfr[s][nt], acc[s][nt][m], 0, 0, 0);
        }
    }
    if (wave > 0) {
#pragma unroll
        for (int s = 0; s < 2; ++s)
#pragma unroll
            for (int nt = 0; nt < 2; ++nt)
#pragma unroll
                for (int m = 0; m < 4; ++m) red[wave - 1][s][nt][m][lane] = acc[s][nt][m];
    }
    if (wave == 1 || wave == 2) {
        const int nb = (wave - 1) * 16;
        for (int i = lane; i < 1024; i += 64) {
            const int node = nb + (i >> 6), oc = i & 63;
            const float hv = hTf[(size_t)(b * NN + n0 + node) * 64 + oc];
            hf[node][oc] = hv;
            gh[node][64 + oc] = bf16s(hv);
            repr[(((size_t)b * 128 + 64 + oc) * NN + (n0 + node)) * TT + t] = hv;
        }
    }
    __syncthreads();
    if (wave == 0) {
#pragma unroll
        for (int nt = 0; nt < 2; ++nt) {
#pragma unroll
            for (int m = 0; m < 4; ++m) {
                f32x4 g = acc[0][nt][m] + acc[1][nt][m];
#pragma unroll
                for (int w = 0; w < 3; ++w) g += red[w][0][nt][m][lane] + red[w][1][nt][m][lane];
                const int node = nt * 16 + lr;
#pragma unroll
                for (int q = 0; q < 4; ++q) gh[node][m * 16 + lq * 4 + q] = bf16s(g[q]);
            }
        }
    }
    __syncthreads();
    {
        f32x4 dacc[2];
#pragma unroll
        for (int nt = 0; nt < 2; ++nt) dacc[nt] = (f32x4){0.f, 0.f, 0.f, 0.f};
#pragma unroll
        for (int ks = 0; ks < 4; ++ks) {
            short8 af = *reinterpret_cast<const short8*>(Wlb + (size_t)(wave * 16 + lr) * 128 + ks * 32 + lq * 8);
#pragma unroll
            for (int nt = 0; nt < 2; ++nt) {
                short8 bfr = *reinterpret_cast<const short8*>(&gh[nt * 16 + lr][ks * 32 + lq * 8]);
                dacc[nt] = __builtin_amdgcn_mfma_f32_16x16x32_bf16(af, bfr, dacc[nt], 0, 0, 0);
            }
        }
        const float pa = prelu_a[0];
#pragma unroll
        for (int nt = 0; nt < 2; ++nt) {
            const int node = nt * 16 + lr;
#pragma unroll
            for (int q = 0; q < 4; ++q) {
                const int oc = wave * 16 + lq * 4 + q;
                float v = dacc[nt][q] + blout2[oc];
                v = (v >= 0.f) ? v : pa * v;
                repr[(((size_t)b * 128 + oc) * NN + (n0 + node)) * TT + t] = v;
                lo_sm[node][oc] = v;
            }
        }
    }
    __syncthreads();
    {
        const int node = threadIdx.x >> 3, sub = threadIdx.x & 7;
        float s = 0.f;
#pragma unroll
        for (int j = sub * 8; j < sub * 8 + 8; ++j)
            s += Wro[j] * lo_sm[node][j] + Wro[64 + j] * hf[node][j];
        s += __shfl_xor(s, 1); s += __shfl_xor(s, 2); s += __shfl_xor(s, 4);
        if (sub == 0) {
            const float xs2 = s + bro[0];
            const int n = n0 + node;
            const int p = b * NN + n;
            const size_t xi = (size_t)p * TT + t;
            imp[xi] = xs2;
            const int mi = mask[xi];
            const float x2 = mi ? x[xi] : xs2;
            const bf16 x2b = __float2bfloat16(x2);
            const bf16 mb = __float2bfloat16((float)mi);
            zb[((size_t)b * 66 + 64) * NN + n] = x2b;
            zb[((size_t)b * 66 + 65) * NN + n] = mb;
            zT[(size_t)p * ZS + 64] = x2b; zT[(size_t)p * ZS + 65] = mb;
            zcT[(size_t)p * ZS + 64] = x2b; zcT[(size_t)p * ZS + 65] = mb;
        }
    }
}

// ---------------- difN1: rh diffusion (R14: 2 n-tiles/wave, double-buffered loads) ----------------
__global__ __launch_bounds__(256) void k_difN(
    const bf16* __restrict__ adjb, const bf16* __restrict__ adj2b,
    const bf16* __restrict__ zcb, bf16* __restrict__ zcT)
{
    const int i = blockIdx.y;
    const int b = i & 1, s = (i >> 1) & 1, ord = i >> 2;
    const int wave = threadIdx.x >> 6, lane = threadIdx.x & 63;
    const int lr = lane & 15, lq = lane >> 4;
    const int n0 = blockIdx.x * 32;
    const int sb = s * 2 + b;
    const bf16* M = (ord ? adj2b : adjb) + ((size_t)sb << 20);
    const bf16* A = M + (size_t)(n0 + lr) * NN + lq * 8;
    const bf16* Xp = zcb + ((size_t)(b * 66 + lr)) * NN + lq * 8;

    f32x4 acc[2][4];
#pragma unroll
    for (int nt = 0; nt < 2; ++nt)
#pragma unroll
        for (int m = 0; m < 4; ++m) acc[nt][m] = (f32x4){0.f, 0.f, 0.f, 0.f};
    const int vbeg = wave * 256;

    short8 bfr[2], af[4];
#pragma unroll
    for (int nt = 0; nt < 2; ++nt)
        bfr[nt] = *reinterpret_cast<const short8*>(A + (size_t)nt * 16 * NN + vbeg);
#pragma unroll
    for (int m = 0; m < 4; ++m)
        af[m] = *reinterpret_cast<const short8*>(Xp + (size_t)m * 16 * NN + vbeg);

#pragma unroll 2
    for (int it = 0; it < 8; ++it) {
        const int vn = vbeg + it * 32 + 32;
        short8 bfr_n[2], af_n[4];
        if (it < 7) {
#pragma unroll
            for (int nt = 0; nt < 2; ++nt)
                bfr_n[nt] = *reinterpret_cast<const short8*>(A + (size_t)nt * 16 * NN + vn);
#pragma unroll
            for (int m = 0; m < 4; ++m)
                af_n[m] = *reinterpret_cast<const short8*>(Xp + (size_t)m * 16 * NN + vn);
        }
#pragma unroll
        for (int nt = 0; nt < 2; ++nt)
#pragma unroll
            for (int m = 0; m < 4; ++m)
                acc[nt][m] = __builtin_amdgcn_mfma_f32_16x16x32_bf16(af[m], bfr[nt], acc[nt][m], 0, 0, 0);
        if (it < 7) {
#pragma unroll
            for (int nt = 0; nt < 2; ++nt) bfr[nt] = bfr_n[nt];
#pragma unroll
            for (int m = 0; m < 4; ++m) af[m] = af_n[m];
        }
    }
    __shared__ f32x4 red[3][2][4][64];
    if (wave > 0) {
#pragma unroll
        for (int nt = 0; nt < 2; ++nt)
#pragma unroll
            for (int m = 0; m < 4; ++m) red[wave - 1][nt][m][lane] = acc[nt][m];
    }
    __syncthreads();
    if (wave == 0) {
#pragma unroll
        for (int nt = 0; nt < 2; ++nt) {
#pragma unroll
            for (int m = 0; m < 4; ++m)
                acc[nt][m] += red[0][nt][m][lane] + red[1][nt][m][lane] + red[2][nt][m][lane];
            const int p = b * NN + n0 + nt * 16 + lr;
            bf16* dst = zcT + (size_t)p * ZS + 68 + (s * 2 + ord) * 68;
#pragma unroll
            for (int m = 0; m < 4; ++m) {
                short4v o = { bf16s(acc[nt][m][0]), bf16s(acc[nt][m][1]),
                              bf16s(acc[nt][m][2]), bf16s(acc[nt][m][3]) };
                *reinterpret_cast<short4v*>(dst + m * 16 + lq * 4) = o;
            }
        }
    }
}

// ---------------- gates: 12 waves = 4 GEMM (r/u) + 8 xd-diffusion (split-K) (R14) ----------------
__global__ __launch_bounds__(768) void k_gates(
    const bf16* __restrict__ Wrub, const bf16* __restrict__ zT,
    const float* __restrict__ br, const float* __restrict__ bu,
    const float* __restrict__ hTf,
    const bf16* __restrict__ adjb, const bf16* __restrict__ adj2b,
    const bf16* __restrict__ zb, const float* __restrict__ Wrux,
    float* __restrict__ uT, bf16* __restrict__ zcb, bf16* __restrict__ zcT)
{
    const int wave = threadIdx.x >> 6, lane = threadIdx.x & 63;
    const int lr = lane & 15, lq = lane >> 4;
    const int p = blockIdx.x * 16 + lr;
    const int b = blockIdx.x >> 6;
    const int n0 = (blockIdx.x & 63) * 16;
    const int n = p & (NN - 1);
    __shared__ float pxd[4][2][2][16];   // [combo][half][chan][lr]
    __shared__ float wxs[128][8];

    f32x4 acc[2];
    acc[0] = (f32x4){0.f, 0.f, 0.f, 0.f};
    acc[1] = (f32x4){0.f, 0.f, 0.f, 0.f};

    if (wave < 4) {
        const int ti = wave * 64 + lane;   // 0..255
        reinterpret_cast<float4*>(&wxs[0][0])[ti] = reinterpret_cast<const float4*>(Wrux)[ti];
        const bf16* B = zT + (size_t)p * ZS;
#pragma unroll 2
        for (int ks = 0; ks < 11; ++ks) {
            short8 bfr = *reinterpret_cast<const short8*>(B + ks * 32 + lq * 8);
#pragma unroll
            for (int mm = 0; mm < 2; ++mm) {
                short8 af = *reinterpret_cast<const short8*>(
                    Wrub + (size_t)(wave * 32 + mm * 16 + lr) * ZS + ks * 32 + lq * 8);
                acc[mm] = __builtin_amdgcn_mfma_f32_16x16x32_bf16(af, bfr, acc[mm], 0, 0, 0);
            }
        }
    } else {
        const int j = wave - 4;            // 0..7
        const int bk = j & 3, half = j >> 2;
        const int s = bk >> 1, ord = bk & 1;
        const bf16* Mp = (ord ? adj2b : adjb) + ((size_t)(s * 2 + b) << 20)
                         + (size_t)(n0 + lr) * NN + lq * 8 + half * 512;
        const bf16* Xp = zb + (size_t)(b * 66 + 64 + lr) * NN + lq * 8 + half * 512;
        const short8 zsh = {0, 0, 0, 0, 0, 0, 0, 0};
        f32x4 a = (f32x4){0.f, 0.f, 0.f, 0.f};
#pragma unroll 4
        for (int it = 0; it < 16; ++it) {
            short8 afv = (lr < 2) ? *reinterpret_cast<const short8*>(Xp + it * 32) : zsh;
            short8 mv = *reinterpret_cast<const short8*>(Mp + it * 32);
            a = __builtin_amdgcn_mfma_f32_16x16x32_bf16(afv, mv, a, 0, 0, 0);
        }
        if (lq == 0) { pxd[bk][half][0][lr] = a[0]; pxd[bk][half][1][lr] = a[1]; }
    }
    __syncthreads();

    if (wave < 4) {
        float xdsum[8];
#pragma unroll
        for (int j2 = 0; j2 < 8; ++j2)
            xdsum[j2] = pxd[j2 >> 1][0][j2 & 1][lr] + pxd[j2 >> 1][1][j2 & 1][lr];
        if (wave < 2) {
#pragma unroll
            for (int mm = 0; mm < 2; ++mm) {
                short4v rq;
#pragma unroll
                for (int q = 0; q < 4; ++q) {
                    const int oc = wave * 32 + mm * 16 + lq * 4 + q;
                    float corr = 0.f;
#pragma unroll
                    for (int j = 0; j < 8; ++j) corr += wxs[oc][j] * xdsum[j];
                    const float rv = sigmoidf_(acc[mm][q] + corr + br[oc]);
                    const float rh = rv * hTf[(size_t)p * 64 + oc];
                    rq[q] = bf16s(rh);
                    zcb[((size_t)b * 66 + oc) * NN + n] = __float2bfloat16(rh);
                }
                *reinterpret_cast<short4v*>(&zcT[(size_t)p * ZS + (wave * 32 + mm * 16) + lq * 4]) = rq;
            }
        } else {
#pragma unroll
            for (int mm = 0; mm < 2; ++mm) {
                f32x4 uq;
#pragma unroll
                for (int q = 0; q < 4; ++q) {
                    const int ocu = (wave - 2) * 32 + mm * 16 + lq * 4 + q;
                    float corr = 0.f;
#pragma unroll
                    for (int j = 0; j < 8; ++j) corr += wxs[64 + ocu][j] * xdsum[j];
                    uq[q] = sigmoidf_(acc[mm][q] + corr + bu[ocu]);
                }
                *reinterpret_cast<f32x4*>(&uT[(size_t)p * 64 + (wave - 2) * 32 + mm * 16 + lq * 4]) = uq;
            }
        }
    } else if (wave < 8 && lq == 0) {
        const int bk = wave - 4;
        const float v0 = pxd[bk][0][0][lr] + pxd[bk][1][0][lr];
        const float v1 = pxd[bk][0][1][lr] + pxd[bk][1][1][lr];
        bf16* dst = zcT + (size_t)p * ZS + 68 + bk * 68 + 64;
        dst[0] = __float2bfloat16(v0);
        dst[1] = __float2bfloat16(v1);
    }
}

// ---------------- cellpre: 4-wave m-split cell + pre(t+1) via LDS transpose (R14) ----------------
__global__ __launch_bounds__(256) void k_cellpre(
    const bf16* __restrict__ Wcb, const bf16* __restrict__ zcT,
    const float* __restrict__ bc, const float* __restrict__ uT,
    float* __restrict__ hTf, bf16* __restrict__ zT, bf16* __restrict__ zb,
    const bf16* __restrict__ Wpre, const float* __restrict__ Wcomb,
    const float* __restrict__ bcomb, const float* __restrict__ bfsp,
    const float* __restrict__ x, const int* __restrict__ mask,
    bf16* __restrict__ yb, float* __restrict__ pred, int tn)
{
    const int wave = threadIdx.x >> 6, lane = threadIdx.x & 63;
    const int lr = lane & 15, lq = lane >> 4;
    const int p = blockIdx.x * 16 + lr;
    const int b = p >> 10, n = p & (NN - 1);
    __shared__ short hsm[16][72];
    __shared__ float xs1s[16];

    {
        const bf16* B = zcT + (size_t)p * ZS;
        f32x4 acc = (f32x4){0.f, 0.f, 0.f, 0.f};
#pragma unroll 2
        for (int ks = 0; ks < 11; ++ks) {
            short8 bfr = *reinterpret_cast<const short8*>(B + ks * 32 + lq * 8);
            short8 af = *reinterpret_cast<const short8*>(Wcb + (size_t)(wave * 16 + lr) * ZS + ks * 32 + lq * 8);
            acc = __builtin_amdgcn_mfma_f32_16x16x32_bf16(af, bfr, acc, 0, 0, 0);
        }
        f32x4 hq;
        short4v hb;
#pragma unroll
        for (int q = 0; q < 4; ++q) {
            const int oc = wave * 16 + lq * 4 + q;
            const float cv = tanhf(acc[q] + bc[oc]);
            const float uv = uT[(size_t)p * 64 + oc];
            const float ho = hTf[(size_t)p * 64 + oc];
            const float hn = uv * ho + (1.f - uv) * cv;
            hq[q] = hn;
            hb[q] = bf16s(hn);
            zb[((size_t)b * 66 + oc) * NN + n] = __float2bfloat16(hn);
        }
        *reinterpret_cast<f32x4*>(&hTf[(size_t)p * 64 + wave * 16 + lq * 4]) = hq;
        *reinterpret_cast<short4v*>(&zT[(size_t)p * ZS + wave * 16 + lq * 4]) = hb;
        *reinterpret_cast<short4v*>(&hsm[lr][wave * 16 + lq * 4]) = hb;
    }
    __syncthreads();

    {
        const int tbase = (wave == 0) ? 0 : 1 + wave * 2;
        const int tcnt = (wave == 0) ? 3 : 2;
        f32x4 acc[3];
#pragma unroll
        for (int m = 0; m < 3; ++m) acc[m] = (f32x4){0.f, 0.f, 0.f, 0.f};
#pragma unroll
        for (int ks = 0; ks < 2; ++ks) {
            short8 bfr = *reinterpret_cast<const short8*>(&hsm[lr][ks * 32 + lq * 8]);
#pragma unroll
            for (int m = 0; m < 3; ++m) {
                if (m < tcnt) {
                    const int mm = tbase + m;
                    short8 af = *reinterpret_cast<const short8*>(Wpre + (size_t)(mm * 16 + lr) * 64 + ks * 32 + lq * 8);
                    acc[m] = __builtin_amdgcn_mfma_f32_16x16x32_bf16(af, bfr, acc[m], 0, 0, 0);
                }
            }
        }
        if (wave == 0 && lq == 0) xs1s[lr] = acc[0][0] + bfsp[0];
        __syncthreads();
        const float xs1 = xs1s[lr];
        const size_t xi = (size_t)p * TT + tn;
        const int mi = mask[xi];
        const float mf = (float)mi;
        const float x1 = mi ? x[xi] : xs1;
        if (wave == 0 && lq == 0) pred[xi] = xs1;
#pragma unroll
        for (int m = 0; m < 3; ++m) {
            if (m < tcnt) {
                const int mm = tbase + m;
#pragma unroll
                for (int q = 0; q < 4; ++q) {
                    const int o = mm * 16 + lq * 4 + q - 1;
                    if (o >= 0 && o < 128) {
                        const float val = acc[m][q] + Wcomb[o * 66] * x1 + Wcomb[o * 66 + 1] * mf + bcomb[o];
                        yb[(size_t)(b * 128 + o) * NN + n] = __float2bfloat16(val);
                    }
                }
            }
        }
    }
}

extern "C" void kernel_launch(void* const* d_in, const int* in_sizes, int n_in,
                              void* d_out, int out_size, void* d_ws, size_t ws_size,
                              hipStream_t stream)
{
    const float* x     = (const float*)d_in[0];
    const int*   mask  = (const int*)  d_in[1];
    const float* adj   = (const float*)d_in[2];
    const float* Wr    = (const float*)d_in[3];
    const float* br    = (const float*)d_in[4];
    const float* Wu    = (const float*)d_in[5];
    const float* bu    = (const float*)d_in[6];
    const float* Wc    = (const float*)d_in[7];
    const float* bc    = (const float*)d_in[8];
    const float* Wfs   = (const float*)d_in[9];
    const float* bfs   = (const float*)d_in[10];
    const float* Wdin  = (const float*)d_in[11];
    const float* bdin  = (const float*)d_in[12];
    const float* Wgc   = (const float*)d_in[13];
    const float* bgc   = (const float*)d_in[14];
    const float* Wlout = (const float*)d_in[15];
    const float* blout = (const float*)d_in[16];
    const float* Wro   = (const float*)d_in[17];
    const float* bro   = (const float*)d_in[18];
    const float* pa    = (const float*)d_in[19];

    float* ws = (float*)d_ws;
    float* Wcomb  = ws + 0;          // 8448
    float* bcomb  = ws + 8448;       // 128
    float* blout2 = ws + 8576;       // 64
    float* Wrux   = ws + 8640;       // 1024
    float* uT     = ws + 272832;     // 131072
    float* hTf    = ws + 403904;     // 131072   <- zero region start
    bf16* bfp   = (bf16*)(ws + 534976);
    bf16* zb    = bfp + 0;           // 135168
    bf16* zcb   = bfp + 135168;      // 135168
    bf16* zT    = bfp + 270336;      // 720896
    bf16* zcT   = bfp + 991232;      // 720896   <- zero region end (bfp+1712128)
    bf16* adjb  = bfp + 1712128;     // 4194304
    bf16* adjtb = bfp + 5906432;     // 4194304
    bf16* adj2b = bfp + 10100736;    // 4194304
    bf16* yb    = bfp + 14295040;    // 262144
    bf16* Wpre  = bfp + 14557184;    // 9216
    bf16* Wrub  = bfp + 14566400;    // 45056
    bf16* Wcb   = bfp + 14611456;    // 22528
    bf16* Wlb   = bfp + 14633984;    // 8192

    float* imp  = (float*)d_out;
    float* pred = imp + (size_t)BB * NN * TT;
    float* repr = imp + (size_t)2 * BB * NN * TT;

    hipLaunchKernelGGL(k_init, dim3(1458), dim3(256), 0, stream,
                       Wgc, bgc, Wdin, bdin, Wlout, blout, Wfs, Wr, Wu, Wc, adj,
                       Wcomb, bcomb, blout2, Wpre, Wrub, Wcb, Wlb, Wrux,
                       adjb, adjtb, hTf);
    hipLaunchKernelGGL(k_a2pre, dim3(640), dim3(256), 0, stream,
                       adjb, adjtb, adj2b, Wpre, zT, Wcomb, bcomb, bfs,
                       x, mask, yb, pred);

    for (int t = 0; t < TT; ++t) {
        // t==0: h == 0, so all h-diffusions are zero — the zero-fill already wrote them.
        const int ny = (t > 0 && t < TT - 1) ? 10 : 2;
        hipLaunchKernelGGL(k_difA, dim3(32, ny), dim3(256), 0, stream,
                           adjb, adj2b, yb, zb, Wlb, blout2, pa, Wro, bro, x, mask,
                           hTf, imp, repr, zb, zcb, zT, zcT, t);
        if (t < TT - 1) {
            hipLaunchKernelGGL(k_gates, dim3(128), dim3(768), 0, stream,
                               Wrub, zT, br, bu, hTf, adjb, adj2b, zb, Wrux,
                               uT, zcb, zcT);
            if (t > 0) {   // t==0: rh == 0, diffusion is zero — zero-fill already wrote it
                hipLaunchKernelGGL(k_difN, dim3(32, 8), dim3(256), 0, stream,
                                   adjb, adj2b, zcb, zcT);
            }
            hipLaunchKernelGGL(k_cellpre, dim3(128), dim3(256), 0, stream,
                               Wcb, zcT, bc, uT, hTf, zT, zb,
                               Wpre, Wcomb, bcomb, bfs, x, mask, yb, pred, t + 1);
        }
    }
}